// Round 9
// baseline (544.906 us; speedup 1.0000x reference)
//
#include <hip/hip_runtime.h>
#include <math.h>

#define CCH 128
#define HH 64
#define WW 64
#define SHD 17
#define NSHIFT (SHD*SHD)   // 289

// ---- workspace layout ----
// float-index offsets:
#define OFF_KEY    0                         // 256 u32 monotone sim-max keys
#define OFF_NPART  256                       // 512*16 f  grd-norm partials [(h*8+csl)][n]
#define OFF_EPART  8448                      // 8*65536 f energy partials [csl][(n*64+h)*64+w]
#define OFF_SCALE  532736                    // 16*289 f
#define OFF_NORMS  537360                    // 16 f grd-norm sums (per image)
#define OFF_SYNC   537376                    // u32[16]: work/done counters (memset 0)
//   sync[0]=claim_prep  sync[1]=prep_done  sync[2]=claim_reduce  sync[3]=A_done
//   sync[4..11]=claim_csl[8]  sync[12]=reduce_done
// byte offsets:
#define OFF_SYNC_B 2149504                   // 537376*4
#define OFF_SATP_B 2162688                   // padded sat bf16: 8 x [h64][slot80][n16][c16]
#define SATP_SLICE_U16 (64*80*16*16)         // 1310720
#define OFF_GRDB_B (OFF_SATP_B + 8*SATP_SLICE_U16*2)   // 23134208
#define GRD_SLICE_U16 (64*64*16*16)          // 1048576
#define OFF_PART_B (OFF_GRDB_B + 8*GRD_SLICE_U16*2)    // 39911424
// part: per corr unit (cross-wave reduced): 68 x 64 f; 1088*4352*4 B = 18.9 MB

typedef __bf16 bf16x8 __attribute__((ext_vector_type(8)));
typedef float floatx4 __attribute__((ext_vector_type(4)));
typedef unsigned short ushort8 __attribute__((ext_vector_type(8)));

#define AS1 __attribute__((address_space(1)))
#define AS3 __attribute__((address_space(3)))

__device__ inline unsigned short f2bf(float f) {
    unsigned x = __float_as_uint(f);
    unsigned r = x + 0x7FFFu + ((x >> 16) & 1u);   // RNE
    return (unsigned short)(r >> 16);
}

__device__ inline void spin_ge(unsigned* c, unsigned tgt, int t) {
    if (t == 0)
        while (__hip_atomic_load(c, __ATOMIC_RELAXED, __HIP_MEMORY_SCOPE_AGENT) < tgt)
            __builtin_amdgcn_s_sleep(2);
    __syncthreads();
    __threadfence();   // acquire: subsequent plain reads see released data
}

// ============ single persistent kernel ============
// R8 post-mortem: GPU work ~90 us vs total 167.7 -> ~75 us is inter-kernel
// serialization across 3 launches. This kernel runs everything in ONE
// dispatch: 512 worker blocks claim units from monotone atomic counters:
//   phase P: 1024 prep units  -> prep_done
//   phase A: per-csl lists (2 scale + 136 corr, strip-major) -> A_done
//   phase B: 289 reduce units -> last-done block computes the 3 scalars.
// Deadlock-free for any residency: waiters wait only on earlier-listed work,
// already claimed by blocks that never wait on later work (no cycles).
// Bodies are byte-identical to R8's measured-good k_prep/scale/corr/reduce.
__global__ __launch_bounds__(256, 2) void k_main(const float* __restrict__ sat,
                                                 const float* __restrict__ grd,
                                                 char* __restrict__ wsb,
                                                 float* __restrict__ out) {
    __shared__ alignas(16) unsigned char smem[81920];
    unsigned* ubc = (unsigned*)(smem + 81912);   // claim broadcast (dead during bodies)
    float* ws = (float*)wsb;
    unsigned* sync = (unsigned*)wsb + OFF_SYNC;
    unsigned short* satp_w = (unsigned short*)(wsb + OFF_SATP_B);
    unsigned short* grdb_w = (unsigned short*)(wsb + OFF_GRDB_B);
    float* part = (float*)(wsb + OFF_PART_B);
    int t = threadIdx.x;
    int bid = blockIdx.x;

    // ---------------- phase P: prep (claimed units 0..1023) ----------------
    for (;;) {
        __syncthreads();
        if (t == 0) *ubc = atomicAdd(&sync[0], 1u);
        __syncthreads();
        unsigned u = *ubc;
        if (u >= 1024u) break;

        int b = (int)u;
        int tensor = b >> 9, h = (b >> 3) & 63, cslp = b & 7;
        const float* src = tensor ? grd : sat;
        unsigned short* tile = (unsigned short*)smem;     // 32 KB
        float* nredp = (float*)(smem + 32768);            // 16 f
        int n = t >> 4, wq = t & 15;

        float en0 = 0.f, en1 = 0.f, en2 = 0.f, en3 = 0.f;
        const float* base = src + ((size_t)(n * CCH + cslp * 16) * 4096) + h * 64 + wq * 4;
        int w0 = wq * 4;
        #pragma unroll
        for (int c = 0; c < 16; ++c) {
            float4 v = *(const float4*)(base + (size_t)c * 4096);
            en0 = fmaf(v.x, v.x, en0); en1 = fmaf(v.y, v.y, en1);
            en2 = fmaf(v.z, v.z, en2); en3 = fmaf(v.w, v.w, en3);
            tile[(w0 + 0) * 256 + ((n + w0 + 0) & 15) * 16 + c] = f2bf(v.x);
            tile[(w0 + 1) * 256 + ((n + w0 + 1) & 15) * 16 + c] = f2bf(v.y);
            tile[(w0 + 2) * 256 + ((n + w0 + 2) & 15) * 16 + c] = f2bf(v.z);
            tile[(w0 + 3) * 256 + ((n + w0 + 3) & 15) * 16 + c] = f2bf(v.w);
        }

        if (tensor == 0) {
            float* eg = ws + OFF_EPART + (size_t)cslp * 65536 + ((size_t)n * 64 + h) * 64 + w0;
            *(float4*)eg = make_float4(en0, en1, en2, en3);
        } else {
            float s = en0 + en1 + en2 + en3;
            #pragma unroll
            for (int off = 8; off; off >>= 1) s += __shfl_xor(s, off);
            if (wq == 0) nredp[n] = s;
        }

        __syncthreads();
        if (tensor == 1 && t < 16)
            ws[OFF_NPART + (size_t)(h * 8 + cslp) * 16 + t] = nredp[t];

        unsigned short* dst = tensor
            ? grdb_w + (size_t)cslp * GRD_SLICE_U16 + (size_t)h * 16384
            : satp_w + (size_t)cslp * SATP_SLICE_U16 + ((size_t)h * 80 + 8) * 256;
        #pragma unroll
        for (int i = 0; i < 8; ++i) {
            int o = i * 256 + t;
            int w = o >> 5, nn = (o >> 1) & 15, c8 = o & 1;
            ushort8 val = *(ushort8*)&tile[w * 256 + ((nn + w) & 15) * 16 + c8 * 8];
            *(ushort8*)&dst[(size_t)o * 8] = val;
        }
        if (tensor == 0) {
            ushort8 z = (ushort8)0;
            #pragma unroll
            for (int i = 0; i < 2; ++i) {
                int o = i * 256 + t;
                int slot = o >> 5, wi = o & 31;
                int ps = slot < 8 ? slot : slot + 64;
                *(ushort8*)&satp_w[(size_t)cslp * SATP_SLICE_U16 +
                                   ((size_t)h * 80 + ps) * 256 + wi * 8] = z;
            }
        }
        __threadfence();
        __syncthreads();
        if (t == 0) atomicAdd(&sync[1], 1u);    // prep unit done (release)
    }
    spin_ge(&sync[1], 1024u, t);                // all prep data visible

    // ---------------- phase A: scale + corr (per-csl lists) ----------------
    int csl = bid & 7;                          // XCD affinity heuristic
    const unsigned short* sats = satp_w + (size_t)csl * SATP_SLICE_U16;
    const unsigned short* grds = grdb_w + (size_t)csl * GRD_SLICE_U16;
    for (;;) {
        __syncthreads();
        if (t == 0) *ubc = atomicAdd(&sync[4 + csl], 1u);
        __syncthreads();
        unsigned u = *ubc;
        if (u >= 138u) break;

        if (u < 2u) {                           // ---- scale/norm unit ----
            int m = csl + 8 * (int)u;
            float* E  = (float*)smem;           // 4096 f
            float* R  = E + 4096;               // 1088 f
            float* nr = R + 1088;               // 256 f
            if (t < 16) ((unsigned*)ws)[OFF_KEY + m * 16 + t] = 0u;   // zero keys
            float s = 0.f;
            for (int j = t; j < 512; j += 256) s += ws[OFF_NPART + (size_t)j * 16 + m];
            nr[t] = s; __syncthreads();
            for (int off = 128; off; off >>= 1) {
                if (t < off) nr[t] += nr[t + off];
                __syncthreads();
            }
            if (t == 0) ws[OFF_NORMS + m] = nr[0];
            const float* ep = ws + OFF_EPART + (size_t)m * 4096;
            for (int i = t; i < 4096; i += 256) {
                float e = 0.f;
                #pragma unroll
                for (int c = 0; c < 8; ++c) e += ep[(size_t)c * 65536 + i];
                E[i] = e;
            }
            __syncthreads();
            for (int i = t; i < 64 * 17; i += 256) {
                int y = i / 17, j = i % 17;
                int x0 = max(0, j - 8), x1 = min(64, j + 56);
                float e = 0.f;
                for (int x = x0; x < x1; ++x) e += E[y * 64 + x];
                R[i] = e;
            }
            __syncthreads();
            float* scale = ws + OFF_SCALE + (size_t)m * NSHIFT;
            for (int idx = t; idx < NSHIFT; idx += 256) {
                int ii = idx / 17, j = idx % 17;
                int y0 = max(0, ii - 8), y1 = min(64, ii + 56);
                float e = 0.f;
                for (int y = y0; y < y1; ++y) e += R[y * 17 + j];
                scale[idx] = 1.f / fmaxf(sqrtf(e), 1e-12f);
            }
        } else {                                // ---- corr unit (R8 body) ----
            int r2  = (int)u - 2;               // strip-major: dyi fast
            int dyi = r2 % 17;
            int hq  = r2 / 17;
            int h0  = hq * 8;
            int wv = t >> 6, l = t & 63;
            int m16 = l & 15, q = l >> 4, jl = q >> 1, c8 = q & 1;
            int wbase = wv * 16;
            const unsigned short* goff = grds + ((wbase + jl) * 16 + m16) * 16 + c8 * 8;
            int hl = max(0, 8 - dyi - h0), hu = min(8, 72 - dyi - h0);

            floatx4 acc[17];
            #pragma unroll
            for (int d = 0; d < 17; ++d) acc[d] = (floatx4)0.f;

            #define STAGE(hs, p)                                                        \
                do {                                                                    \
                    _Pragma("unroll")                                                   \
                    for (int i_ = 0; i_ < 10; ++i_) {                                   \
                        const unsigned short* g_ = sats + (size_t)(hs) * 20480          \
                                                 + wv * 5120 + i_ * 512 + l * 8;        \
                        __builtin_amdgcn_global_load_lds((AS1 void*)(unsigned short*)g_,\
                            (AS3 void*)(smem + (p) * 40960 + wv * 10240 + i_ * 1024 + l * 16), \
                            16, 0, 0);                                                  \
                    }                                                                   \
                } while (0)

            if (hl < hu) {
                int hs0 = h0 + hl + dyi - 8;
                STAGE(hs0, 0);
                bf16x8 Bc[8], Bn[8];
                #pragma unroll
                for (int bi = 0; bi < 8; ++bi)
                    Bc[bi] = *(const bf16x8*)(goff + (size_t)(h0 + hl) * 16384 + bi * 512);

                for (int hh = hl; hh < hu; ++hh) {
                    __syncthreads();
                    int p = (hh - hl) & 1;
                    if (hh + 1 < hu) {
                        STAGE(hs0 + (hh - hl) + 1, p ^ 1);
                        #pragma unroll
                        for (int bi = 0; bi < 8; ++bi)
                            Bn[bi] = *(const bf16x8*)(goff + (size_t)(h0 + hh + 1) * 16384 + bi * 512);
                    }
                    const unsigned char* aptr = smem + p * 40960 + jl * 512 + m16 * 32 + c8 * 16;
                    bf16x8 A = *(const bf16x8*)(aptr + (size_t)wbase * 512);
                    #pragma unroll
                    for (int wo = 0; wo < 31; ++wo) {
                        bf16x8 An = A;
                        if (wo < 30) An = *(const bf16x8*)(aptr + (size_t)(wbase + wo + 1) * 512);
                        #pragma unroll
                        for (int bi = 0; bi < 8; ++bi) {
                            const int dxi = wo - 2 * bi;
                            if (dxi >= 0 && dxi <= 16)
                                acc[dxi] = __builtin_amdgcn_mfma_f32_16x16x32_bf16(A, Bc[bi], acc[dxi], 0, 0, 0);
                        }
                        A = An;
                    }
                    #pragma unroll
                    for (int bi = 0; bi < 8; ++bi) Bc[bi] = Bn[bi];
                }
            }
            #undef STAGE

            __syncthreads();
            float* red = (float*)smem;          // 69632 B
            #pragma unroll
            for (int dxi = 0; dxi < 17; ++dxi)
                #pragma unroll
                for (int r = 0; r < 4; ++r)
                    red[(size_t)(wv * 68 + dxi * 4 + r) * 64 + l] = acc[dxi][r];
            __syncthreads();
            float* pw = part + (size_t)(r2 * 8 + csl) * 4352;
            #pragma unroll
            for (int k = 0; k < 17; ++k) {
                int row = wv * 17 + k;
                float s = red[(size_t)(0 * 68 + row) * 64 + l]
                        + red[(size_t)(1 * 68 + row) * 64 + l]
                        + red[(size_t)(2 * 68 + row) * 64 + l]
                        + red[(size_t)(3 * 68 + row) * 64 + l];
                pw[(size_t)row * 64 + l] = s;
            }
        }
        __threadfence();
        __syncthreads();
        if (t == 0) atomicAdd(&sync[3], 1u);    // A-unit done (release)
    }
    spin_ge(&sync[3], 1104u, t);                // all part/scale/norms visible

    // ---------------- phase B: reduce + last-done final ----------------
    for (;;) {
        __syncthreads();
        if (t == 0) *ubc = atomicAdd(&sync[2], 1u);
        __syncthreads();
        unsigned u = *ubc;
        if (u >= 289u) break;

        int dyi = (int)u / 17, dxi = (int)u % 17;
        int l = t & 63, r = t >> 6;
        size_t eo = (size_t)(dxi * 4 + r) * 64 + l;
        float s = 0.f;
        for (int hq = 0; hq < 8; ++hq) {
            #pragma unroll
            for (int c = 0; c < 8; ++c) {
                size_t blk = (size_t)((hq * 17 + dyi) * 8 + c);
                s += part[blk * 4352 + eo];
            }
        }
        int n = l & 15, q = l >> 4, m = q * 4 + r;
        float val = s * ws[OFF_SCALE + m * NSHIFT + dyi * 17 + dxi];
        int iv = __float_as_int(val);
        unsigned key = (iv >= 0) ? ((unsigned)iv | 0x80000000u) : (unsigned)(~iv);
        atomicMax((unsigned*)ws + OFF_KEY + m * 16 + n, key);

        unsigned* dflag = (unsigned*)smem;
        __syncthreads();
        if (t == 0) { __threadfence(); *dflag = atomicAdd(&sync[12], 1u); }
        __syncthreads();
        bool last = (*dflag == 288u);
        __syncthreads();
        if (!last) continue;

        // ---- final: 3 scalars (runs once, all keys complete) ----
        float* dist_s = (float*)(smem + 16);    // 256 f
        float* pos_s  = dist_s + 256;           // 16 f
        float* red2   = pos_s + 16;             // 256 f
        float* minv   = red2 + 256;             // 16 f
        unsigned uk = atomicOr((unsigned*)ws + OFF_KEY + t, 0u);
        int iv2 = (uk & 0x80000000u) ? (int)(uk & 0x7fffffffu) : ~(int)uk;
        float best = __int_as_float(iv2);
        int mm = t >> 4, nn = t & 15;
        float Ng  = sqrtf(ws[OFF_NORMS + nn]);
        float sim = best / fmaxf(Ng, 1e-12f);
        float d   = 2.f - 2.f * sim;
        dist_s[t] = d;
        if (mm == nn) pos_s[mm] = d;
        __syncthreads();

        float x1 = (pos_s[nn] - d) * 10.f;
        float x2 = (pos_s[mm] - d) * 10.f;
        float sp1 = x1 > 20.f ? x1 : log1pf(expf(x1));
        float sp2 = x2 > 20.f ? x2 : log1pf(expf(x2));
        red2[t] = sp1 + sp2;
        __syncthreads();
        for (int off = 128; off; off >>= 1) {
            if (t < off) red2[t] += red2[t + off];
            __syncthreads();
        }
        if (t < 16) {
            float mv = 1e30f;
            for (int k = 0; k < 16; ++k) mv = fminf(mv, dist_s[t * 16 + k]);
            minv[t] = mv;
        }
        __syncthreads();
        if (t == 0) {
            float psum = 0.f, msum = 0.f;
            for (int qq = 0; qq < 16; ++qq) { psum += pos_s[qq]; msum += minv[qq]; }
            out[0] = red2[0] / 48.f;
            out[1] = psum / 16.f;
            out[2] = msum / 16.f;
        }
    }
}

extern "C" void kernel_launch(void* const* d_in, const int* in_sizes, int n_in,
                              void* d_out, int out_size, void* d_ws, size_t ws_size,
                              hipStream_t stream) {
    const float* sat = (const float*)d_in[0];
    const float* grd = (const float*)d_in[1];
    float* out = (float*)d_out;

    hipMemsetAsync((char*)d_ws + OFF_SYNC_B, 0, 64, stream);   // zero sync counters
    k_main<<<512, 256, 0, stream>>>(sat, grd, (char*)d_ws, out);
}

// Round 10
// 166.878 us; speedup vs baseline: 3.2653x; 3.2653x over previous
//
#include <hip/hip_runtime.h>
#include <math.h>

#define CCH 128
#define HH 64
#define WW 64
#define SHD 17
#define NSHIFT (SHD*SHD)   // 289

// ---- workspace layout ----
// float-index offsets:
#define OFF_KEY    0                         // 256 u32 monotone sim-max keys
#define OFF_NPART  256                       // 512*16 f  grd-norm partials [(h*8+csl)][n]
#define OFF_EPART  8448                      // 8*65536 f energy partials [csl][(n*64+h)*64+w]
#define OFF_SCALE  532736                    // 16*289 f
#define OFF_NORMS  537360                    // 16 f grd-norm sums (per image)
#define OFF_CNT    537376                    // u32-index: k_reduce completion counter
// byte offsets:
#define OFF_SATP_B 2162688                   // padded sat bf16: 8 x [h64][slot80][n16][c16]
#define SATP_SLICE_U16 (64*80*16*16)         // 1310720
#define OFF_GRDB_B (OFF_SATP_B + 8*SATP_SLICE_U16*2)   // 23134208
#define GRD_SLICE_U16 (64*64*16*16)          // 1048576
#define OFF_PART_B (OFF_GRDB_B + 8*GRD_SLICE_U16*2)    // 39911424
#define NBLK_CORR 1104                       // 16 fused scale blocks FIRST + 1088 corr
// part: per corr block (cross-wave reduced): 68 x 64 f; 1088*4352*4 B = 18.9 MB

typedef __bf16 bf16x8 __attribute__((ext_vector_type(8)));
typedef float floatx4 __attribute__((ext_vector_type(4)));
typedef unsigned short ushort8 __attribute__((ext_vector_type(8)));
typedef unsigned int uint4v __attribute__((ext_vector_type(4)));

#define AS1 __attribute__((address_space(1)))
#define AS3 __attribute__((address_space(3)))

__device__ inline unsigned short f2bf(float f) {
    unsigned x = __float_as_uint(f);
    unsigned r = x + 0x7FFFu + ((x >> 16) & 1u);   // RNE
    return (unsigned short)(r >> 16);
}

// ---------------- K1: convert + transpose + norm/energy partials ----------
// R9 post-mortem exposed the old tile path: ~1.8M LDS bank conflicts
// (16-way on u16 tile writes), 32KB LDS round-trip, 2 barriers/unit, and an
// LDS-capped occupancy -- against a 20us HBM roofline. This version does the
// transpose IN REGISTERS: same known-good float4 load pattern; bf16 pairs
// packed into pk[4][8] u32 during the c-loop; each w-slot stored directly as
// two 16B stores (512B-contiguous per 16-lane n-group). No tile, no
// conflicts, no barriers (grd-norm keeps its 16-lane shfl + 16f nred).
__global__ __launch_bounds__(256) void k_prep(const float* __restrict__ sat,
                                              const float* __restrict__ grd,
                                              float* __restrict__ ws) {
    __shared__ float nred[16];
    int b = blockIdx.x;
    int tensor = b >> 9, h = (b >> 3) & 63, csl = b & 7;
    const float* src = tensor ? grd : sat;
    unsigned short* dstS = (unsigned short*)((char*)ws + OFF_SATP_B);
    unsigned short* dstG = (unsigned short*)((char*)ws + OFF_GRDB_B);
    int t = threadIdx.x;
    int n = t >> 4, wq = t & 15;
    int w0 = wq * 4;

    float en0 = 0.f, en1 = 0.f, en2 = 0.f, en3 = 0.f;
    const float* base = src + ((size_t)(n * CCH + csl * 16) * 4096) + h * 64 + w0;
    unsigned pk[4][8];                 // [w-lane][c-pair] : bf16(c even)|bf16(c odd)<<16
    #pragma unroll
    for (int c2 = 0; c2 < 8; ++c2) {
        float4 a = *(const float4*)(base + (size_t)(2 * c2) * 4096);
        float4 q = *(const float4*)(base + (size_t)(2 * c2 + 1) * 4096);
        en0 = fmaf(a.x, a.x, en0); en0 = fmaf(q.x, q.x, en0);
        en1 = fmaf(a.y, a.y, en1); en1 = fmaf(q.y, q.y, en1);
        en2 = fmaf(a.z, a.z, en2); en2 = fmaf(q.z, q.z, en2);
        en3 = fmaf(a.w, a.w, en3); en3 = fmaf(q.w, q.w, en3);
        pk[0][c2] = (unsigned)f2bf(a.x) | ((unsigned)f2bf(q.x) << 16);
        pk[1][c2] = (unsigned)f2bf(a.y) | ((unsigned)f2bf(q.y) << 16);
        pk[2][c2] = (unsigned)f2bf(a.z) | ((unsigned)f2bf(q.z) << 16);
        pk[3][c2] = (unsigned)f2bf(a.w) | ((unsigned)f2bf(q.w) << 16);
    }

    if (tensor == 0) {
        float* eg = ws + OFF_EPART + (size_t)csl * 65536 + ((size_t)n * 64 + h) * 64 + w0;
        *(float4*)eg = make_float4(en0, en1, en2, en3);   // plain partial store
        // direct transposed stores: slot = h*80 + 8 + w, [n16][c16] u16
        unsigned short* ds = dstS + (size_t)csl * SATP_SLICE_U16
                           + ((size_t)h * 80 + 8 + w0) * 256 + n * 16;
        #pragma unroll
        for (int k = 0; k < 4; ++k) {
            *(uint4v*)&ds[(size_t)k * 256]     = *(uint4v*)&pk[k][0];   // c 0..7
            *(uint4v*)&ds[(size_t)k * 256 + 8] = *(uint4v*)&pk[k][4];   // c 8..15
        }
        // zero the 16 pad slots (0..7, 72..79) for this (h,csl)
        ushort8 z = (ushort8)0;
        #pragma unroll
        for (int i = 0; i < 2; ++i) {
            int o = i * 256 + t;
            int slot = o >> 5, wi = o & 31;
            int ps = slot < 8 ? slot : slot + 64;
            *(ushort8*)&dstS[(size_t)csl * SATP_SLICE_U16 +
                             ((size_t)h * 80 + ps) * 256 + wi * 8] = z;
        }
    } else {
        float s = en0 + en1 + en2 + en3;
        #pragma unroll
        for (int off = 8; off; off >>= 1) s += __shfl_xor(s, off);  // 16-lane group
        if (wq == 0) nred[n] = s;
        unsigned short* dg = dstG + (size_t)csl * GRD_SLICE_U16
                           + ((size_t)h * 64 + w0) * 256 + n * 16;
        #pragma unroll
        for (int k = 0; k < 4; ++k) {
            *(uint4v*)&dg[(size_t)k * 256]     = *(uint4v*)&pk[k][0];
            *(uint4v*)&dg[(size_t)k * 256 + 8] = *(uint4v*)&pk[k][4];
        }
        __syncthreads();
        if (t < 16)
            ws[OFF_NPART + (size_t)(h * 8 + csl) * 16 + t] = nred[t];
    }
}

// ---------------- K3: MFMA corr + fused scale/norm HEAD blocks ------------
// (R8 verbatim -- best measured: 62.4 us, MfmaUtil 47.5%.)
__global__ __launch_bounds__(256, 2) void k_corr(const unsigned short* __restrict__ satp,
                                                 const unsigned short* __restrict__ grdb,
                                                 float* __restrict__ part,
                                                 float* __restrict__ ws) {
    __shared__ alignas(16) unsigned char smem[81920];
    int b = blockIdx.x;
    int t = threadIdx.x;

    if (b < 16) {                      // ---- fused scale/norm block (early) ----
        int m = b;
        float* E  = (float*)smem;      // 4096 f
        float* R  = E + 4096;          // 1088 f
        float* nr = R + 1088;          // 256 f
        if (t < 16) ((unsigned*)ws)[OFF_KEY + m * 16 + t] = 0u;   // zero sim-max keys
        if (m == 0 && t == 0) ((unsigned*)ws)[OFF_CNT] = 0u;      // zero done-counter
        float s = 0.f;
        for (int j = t; j < 512; j += 256) s += ws[OFF_NPART + (size_t)j * 16 + m];
        nr[t] = s; __syncthreads();
        for (int off = 128; off; off >>= 1) {
            if (t < off) nr[t] += nr[t + off];
            __syncthreads();
        }
        if (t == 0) ws[OFF_NORMS + m] = nr[0];
        const float* ep = ws + OFF_EPART + (size_t)m * 4096;
        for (int i = t; i < 4096; i += 256) {
            float e = 0.f;
            #pragma unroll
            for (int c = 0; c < 8; ++c) e += ep[(size_t)c * 65536 + i];
            E[i] = e;
        }
        __syncthreads();
        for (int i = t; i < 64 * 17; i += 256) {
            int y = i / 17, j = i % 17;
            int x0 = max(0, j - 8), x1 = min(64, j + 56);
            float e = 0.f;
            for (int x = x0; x < x1; ++x) e += E[y * 64 + x];
            R[i] = e;
        }
        __syncthreads();
        float* scale = ws + OFF_SCALE + (size_t)m * NSHIFT;
        for (int idx = t; idx < NSHIFT; idx += 256) {
            int ii = idx / 17, j = idx % 17;
            int y0 = max(0, ii - 8), y1 = min(64, ii + 56);
            float e = 0.f;
            for (int y = y0; y < y1; ++y) e += R[y * 17 + j];
            scale[idx] = 1.f / fmaxf(sqrtf(e), 1e-12f);
        }
        return;
    }

    // ---- corr block (R0 structure: strip-major order, depth-1 A pipe) ----
    int bc  = b - 16;                  // 0..1087
    int csl = bc & 7;                  // XCD low bits: csl-locality per XCD
    int r2  = bc >> 3;
    int dyi = r2 % 17;                 // fast axis: L2 keeps strip working-set
    int hq  = r2 / 17;                 // 0..7
    int h0  = hq * 8;
    int wv = t >> 6, l = t & 63;
    int m16 = l & 15, q = l >> 4, jl = q >> 1, c8 = q & 1;
    int wbase = wv * 16;

    const unsigned short* sats = satp + (size_t)csl * SATP_SLICE_U16;
    const unsigned short* grds = grdb + (size_t)csl * GRD_SLICE_U16;
    const unsigned short* goff = grds + ((wbase + jl) * 16 + m16) * 16 + c8 * 8;
    int hl = max(0, 8 - dyi - h0), hu = min(8, 72 - dyi - h0);

    floatx4 acc[17];
    #pragma unroll
    for (int d = 0; d < 17; ++d) acc[d] = (floatx4)0.f;

    #define STAGE(hs, p)                                                            \
        do {                                                                        \
            _Pragma("unroll")                                                       \
            for (int i_ = 0; i_ < 10; ++i_) {                                       \
                const unsigned short* g_ = sats + (size_t)(hs) * 20480              \
                                         + wv * 5120 + i_ * 512 + l * 8;            \
                __builtin_amdgcn_global_load_lds((AS1 void*)(unsigned short*)g_,    \
                    (AS3 void*)(smem + (p) * 40960 + wv * 10240 + i_ * 1024 + l * 16), \
                    16, 0, 0);                                                      \
            }                                                                       \
        } while (0)

    if (hl < hu) {
        int hs0 = h0 + hl + dyi - 8;
        STAGE(hs0, 0);
        bf16x8 Bc[8], Bn[8];
        #pragma unroll
        for (int bi = 0; bi < 8; ++bi)
            Bc[bi] = *(const bf16x8*)(goff + (size_t)(h0 + hl) * 16384 + bi * 512);

        for (int hh = hl; hh < hu; ++hh) {
            __syncthreads();                     // staged buf[hh&1] ready
            int p = (hh - hl) & 1;
            if (hh + 1 < hu) {
                STAGE(hs0 + (hh - hl) + 1, p ^ 1);
                #pragma unroll
                for (int bi = 0; bi < 8; ++bi)
                    Bn[bi] = *(const bf16x8*)(goff + (size_t)(h0 + hh + 1) * 16384 + bi * 512);
            }
            const unsigned char* aptr = smem + p * 40960 + jl * 512 + m16 * 32 + c8 * 16;
            bf16x8 A = *(const bf16x8*)(aptr + (size_t)wbase * 512);
            #pragma unroll
            for (int wo = 0; wo < 31; ++wo) {    // slot = wbase + wo (+jl)
                bf16x8 An = A;
                if (wo < 30) An = *(const bf16x8*)(aptr + (size_t)(wbase + wo + 1) * 512);
                #pragma unroll
                for (int bi = 0; bi < 8; ++bi) {
                    const int dxi = wo - 2 * bi;   // compile-time after unroll
                    if (dxi >= 0 && dxi <= 16)
                        acc[dxi] = __builtin_amdgcn_mfma_f32_16x16x32_bf16(A, Bc[bi], acc[dxi], 0, 0, 0);
                }
                A = An;
            }
            #pragma unroll
            for (int bi = 0; bi < 8; ++bi) Bc[bi] = Bn[bi];
        }
    }
    #undef STAGE

    // ---- cross-wave reduction epilogue: part traffic /4 ----
    __syncthreads();                    // all waves done reading staged smem
    float* red = (float*)smem;          // 4*68*64*4 = 69632 B <= 81920
    #pragma unroll
    for (int dxi = 0; dxi < 17; ++dxi)
        #pragma unroll
        for (int r = 0; r < 4; ++r)
            red[(size_t)(wv * 68 + dxi * 4 + r) * 64 + l] = acc[dxi][r];
    __syncthreads();
    float* pw = part + (size_t)bc * 4352;
    #pragma unroll
    for (int k = 0; k < 17; ++k) {
        int row = wv * 17 + k;
        float s = red[(size_t)(0 * 68 + row) * 64 + l]
                + red[(size_t)(1 * 68 + row) * 64 + l]
                + red[(size_t)(2 * 68 + row) * 64 + l]
                + red[(size_t)(3 * 68 + row) * 64 + l];
        pw[(size_t)row * 64 + l] = s;
    }
}

// ---------------- K4: reduce + scale + sim-max + fused final --------------
__global__ void k_reduce(const float* __restrict__ part, float* __restrict__ ws,
                         float* __restrict__ out) {
    int b = blockIdx.x;            // 289
    int dyi = b / 17, dxi = b % 17;
    int t = threadIdx.x;
    int l = t & 63, r = t >> 6;
    size_t eo = (size_t)(dxi * 4 + r) * 64 + l;
    float s = 0.f;
    for (int hq = 0; hq < 8; ++hq) {
        #pragma unroll
        for (int csl = 0; csl < 8; ++csl) {
            size_t blk = (size_t)((hq * 17 + dyi) * 8 + csl);
            s += part[blk * 4352 + eo];
        }
    }
    int n = l & 15, q = l >> 4, m = q * 4 + r;
    float val = s * ws[OFF_SCALE + m * NSHIFT + dyi * 17 + dxi];
    int iv = __float_as_int(val);
    unsigned key = (iv >= 0) ? ((unsigned)iv | 0x80000000u) : (unsigned)(~iv);
    atomicMax((unsigned*)ws + OFF_KEY + m * 16 + n, key);

    // ---- last-block-done fused epilogue (was k_final) ----
    __shared__ unsigned done;
    __syncthreads();
    if (t == 0) {
        __threadfence();               // publish this block's atomicMax results
        done = atomicAdd((unsigned*)ws + OFF_CNT, 1u);
    }
    __syncthreads();
    if (done != 288) return;           // only the last-finishing block proceeds
    __threadfence();                   // acquire side

    __shared__ float dist_s[256];
    __shared__ float pos_s[16];
    __shared__ float red2[256];
    __shared__ float minv[16];
    unsigned u = atomicOr((unsigned*)ws + OFF_KEY + t, 0u);
    int iv2 = (u & 0x80000000u) ? (int)(u & 0x7fffffffu) : ~(int)u;
    float best = __int_as_float(iv2);
    int mm = t >> 4, nn = t & 15;
    float Ng  = sqrtf(ws[OFF_NORMS + nn]);
    float sim = best / fmaxf(Ng, 1e-12f);
    float d   = 2.f - 2.f * sim;
    dist_s[t] = d;
    if (mm == nn) pos_s[mm] = d;
    __syncthreads();

    float x1 = (pos_s[nn] - d) * 10.f;
    float x2 = (pos_s[mm] - d) * 10.f;
    float sp1 = x1 > 20.f ? x1 : log1pf(expf(x1));
    float sp2 = x2 > 20.f ? x2 : log1pf(expf(x2));
    red2[t] = sp1 + sp2;
    __syncthreads();
    for (int off = 128; off; off >>= 1) {
        if (t < off) red2[t] += red2[t + off];
        __syncthreads();
    }
    if (t < 16) {
        float mv = 1e30f;
        for (int k = 0; k < 16; ++k) mv = fminf(mv, dist_s[t * 16 + k]);
        minv[t] = mv;
    }
    __syncthreads();
    if (t == 0) {
        float psum = 0.f, msum = 0.f;
        for (int qq = 0; qq < 16; ++qq) { psum += pos_s[qq]; msum += minv[qq]; }
        out[0] = red2[0] / 48.f;
        out[1] = psum / 16.f;
        out[2] = msum / 16.f;
    }
}

extern "C" void kernel_launch(void* const* d_in, const int* in_sizes, int n_in,
                              void* d_out, int out_size, void* d_ws, size_t ws_size,
                              hipStream_t stream) {
    const float* sat = (const float*)d_in[0];
    const float* grd = (const float*)d_in[1];
    float* out = (float*)d_out;
    float* ws  = (float*)d_ws;
    const unsigned short* satp = (const unsigned short*)((char*)d_ws + OFF_SATP_B);
    const unsigned short* grdb = (const unsigned short*)((char*)d_ws + OFF_GRDB_B);
    float* part = (float*)((char*)d_ws + OFF_PART_B);

    k_prep  <<<1024,      256, 0, stream>>>(sat, grd, ws);
    k_corr  <<<NBLK_CORR, 256, 0, stream>>>(satp, grdb, part, ws);
    k_reduce<<<NSHIFT,    256, 0, stream>>>(part, ws, out);
}

// Round 11
// 166.788 us; speedup vs baseline: 3.2670x; 1.0005x over previous
//
#include <hip/hip_runtime.h>
#include <math.h>

#define CCH 128
#define HH 64
#define WW 64
#define SHD 17
#define NSHIFT (SHD*SHD)   // 289

// ---- workspace layout ----
// float-index offsets:
#define OFF_KEY    0                         // 256 u32 monotone sim-max keys
#define OFF_NPART  256                       // 512*16 f  grd-norm partials [(h*8+csl)][n]
#define OFF_EPART  8448                      // 8*65536 f energy partials [csl][(n*64+h)*64+w]
#define OFF_SCALE  532736                    // 16*289 f
#define OFF_NORMS  537360                    // 16 f grd-norm sums (per image)
#define OFF_CNT    537376                    // u32-index: k_reduce completion counter
// byte offsets:
#define OFF_SATP_B 2162688                   // padded sat bf16: 8 x [h64][slot80][n16][c16]
#define SATP_SLICE_U16 (64*80*16*16)         // 1310720
#define OFF_GRDB_B (OFF_SATP_B + 8*SATP_SLICE_U16*2)   // 23134208
#define GRD_SLICE_U16 (64*64*16*16)          // 1048576
#define OFF_PART_B (OFF_GRDB_B + 8*GRD_SLICE_U16*2)    // 39911424
#define NBLK_CORR 1104                       // 16 fused scale blocks FIRST + 1088 corr
// part: per corr block (cross-wave reduced): 68 x 64 f; 1088*4352*4 B = 18.9 MB

typedef __bf16 bf16x8 __attribute__((ext_vector_type(8)));
typedef float floatx4 __attribute__((ext_vector_type(4)));
typedef unsigned short ushort8 __attribute__((ext_vector_type(8)));
typedef unsigned int uint4v __attribute__((ext_vector_type(4)));

#define AS1 __attribute__((address_space(1)))
#define AS3 __attribute__((address_space(3)))

__device__ inline unsigned short f2bf(float f) {
    unsigned x = __float_as_uint(f);
    unsigned r = x + 0x7FFFu + ((x >> 16) & 1u);   // RNE
    return (unsigned short)(r >> 16);
}

// ---------------- K1: convert + transpose + norm/energy partials ----------
// R8 prep: LDS transpose, 16-way write conflicts, coalesced stores.
// R10 prep: register transpose, conflict-free, but 16B stores at 2KB stride
// (1 cacheline/lane). Both measured ~equal -> each has one flaw. This one
// fixes both: register pack -> XOR-swizzled LDS write (bank field becomes
// (2(n&3)+half)^(wq&7): all 8 slots of the 128B window tiled 8x = minimal,
// conflict-free) -> linear LDS read (conflict-free) -> coalesced global
// stores (permutation confined to each 512B w-region). One barrier.
__global__ __launch_bounds__(256) void k_prep(const float* __restrict__ sat,
                                              const float* __restrict__ grd,
                                              float* __restrict__ ws) {
    __shared__ alignas(16) unsigned short tile[64 * 256];   // 32 KB swizzled
    __shared__ float nred[16];
    int b = blockIdx.x;
    int tensor = b >> 9, h = (b >> 3) & 63, csl = b & 7;
    const float* src = tensor ? grd : sat;
    unsigned short* dstS = (unsigned short*)((char*)ws + OFF_SATP_B);
    unsigned short* dstG = (unsigned short*)((char*)ws + OFF_GRDB_B);
    int t = threadIdx.x;
    int n = t >> 4, wq = t & 15;
    int w0 = wq * 4;

    float en0 = 0.f, en1 = 0.f, en2 = 0.f, en3 = 0.f;
    const float* base = src + ((size_t)(n * CCH + csl * 16) * 4096) + h * 64 + w0;
    unsigned pk[4][8];                 // [w-lane][c-pair] : bf16(c even)|bf16(c odd)<<16
    #pragma unroll
    for (int c2 = 0; c2 < 8; ++c2) {
        float4 a = *(const float4*)(base + (size_t)(2 * c2) * 4096);
        float4 q = *(const float4*)(base + (size_t)(2 * c2 + 1) * 4096);
        en0 = fmaf(a.x, a.x, en0); en0 = fmaf(q.x, q.x, en0);
        en1 = fmaf(a.y, a.y, en1); en1 = fmaf(q.y, q.y, en1);
        en2 = fmaf(a.z, a.z, en2); en2 = fmaf(q.z, q.z, en2);
        en3 = fmaf(a.w, a.w, en3); en3 = fmaf(q.w, q.w, en3);
        pk[0][c2] = (unsigned)f2bf(a.x) | ((unsigned)f2bf(q.x) << 16);
        pk[1][c2] = (unsigned)f2bf(a.y) | ((unsigned)f2bf(q.y) << 16);
        pk[2][c2] = (unsigned)f2bf(a.z) | ((unsigned)f2bf(q.z) << 16);
        pk[3][c2] = (unsigned)f2bf(a.w) | ((unsigned)f2bf(q.w) << 16);
    }

    // swizzled LDS write: chunk(w,n,half) at (w*512+n*32+half*16)^((wq&7)<<4)
    // (writer's wq == w>>2 since w = 4*wq+k, k<4 -> reader can un-swizzle)
    unsigned swz = (unsigned)(wq & 7) << 4;
    #pragma unroll
    for (int k = 0; k < 4; ++k) {
        unsigned ba = (unsigned)((w0 + k) * 512 + n * 32);
        *(uint4v*)((char*)tile + ((ba) ^ swz))      = *(uint4v*)&pk[k][0];  // c 0..7
        *(uint4v*)((char*)tile + ((ba + 16) ^ swz)) = *(uint4v*)&pk[k][4];  // c 8..15
    }

    if (tensor == 0) {
        float* eg = ws + OFF_EPART + (size_t)csl * 65536 + ((size_t)n * 64 + h) * 64 + w0;
        *(float4*)eg = make_float4(en0, en1, en2, en3);   // plain partial store
    } else {
        float s = en0 + en1 + en2 + en3;
        #pragma unroll
        for (int off = 8; off; off >>= 1) s += __shfl_xor(s, off);  // 16-lane group
        if (wq == 0) nred[n] = s;
    }

    __syncthreads();
    if (tensor == 1 && t < 16)
        ws[OFF_NPART + (size_t)(h * 8 + csl) * 16 + t] = nred[t];

    // copy LDS -> global: linear physical reads (conflict-free), un-swizzle
    // to find the chunk's (w,n,half), coalesced 512B-window global writes.
    unsigned short* dst = tensor
        ? dstG + (size_t)csl * GRD_SLICE_U16 + (size_t)h * 16384
        : dstS + (size_t)csl * SATP_SLICE_U16 + ((size_t)h * 80 + 8) * 256;
    #pragma unroll
    for (int i = 0; i < 8; ++i) {
        unsigned o  = (unsigned)(i * 256 + t);     // 16B chunk index, 0..2047
        unsigned pa = o * 16u;                      // physical byte addr
        unsigned w  = pa >> 9;                      // XOR confined below bit 7
        unsigned la = pa ^ (((w >> 2) & 7u) << 4);  // logical byte addr
        unsigned cn   = (la >> 5) & 15u;            // n
        unsigned half = (la >> 4) & 1u;
        ushort8 val = *(ushort8*)((char*)tile + pa);
        *(ushort8*)&dst[(size_t)w * 256 + cn * 16 + half * 8] = val;
    }
    if (tensor == 0) {
        ushort8 z = (ushort8)0;
        #pragma unroll
        for (int i = 0; i < 2; ++i) {
            int o = i * 256 + t;
            int slot = o >> 5, wi = o & 31;
            int ps = slot < 8 ? slot : slot + 64;
            *(ushort8*)&dstS[(size_t)csl * SATP_SLICE_U16 +
                             ((size_t)h * 80 + ps) * 256 + wi * 8] = z;
        }
    }
}

// ---------------- K3: MFMA corr + fused scale/norm HEAD blocks ------------
// (R8 verbatim -- best measured: 62.4 us, MfmaUtil 47.5%.)
__global__ __launch_bounds__(256, 2) void k_corr(const unsigned short* __restrict__ satp,
                                                 const unsigned short* __restrict__ grdb,
                                                 float* __restrict__ part,
                                                 float* __restrict__ ws) {
    __shared__ alignas(16) unsigned char smem[81920];
    int b = blockIdx.x;
    int t = threadIdx.x;

    if (b < 16) {                      // ---- fused scale/norm block (early) ----
        int m = b;
        float* E  = (float*)smem;      // 4096 f
        float* R  = E + 4096;          // 1088 f
        float* nr = R + 1088;          // 256 f
        if (t < 16) ((unsigned*)ws)[OFF_KEY + m * 16 + t] = 0u;   // zero sim-max keys
        if (m == 0 && t == 0) ((unsigned*)ws)[OFF_CNT] = 0u;      // zero done-counter
        float s = 0.f;
        for (int j = t; j < 512; j += 256) s += ws[OFF_NPART + (size_t)j * 16 + m];
        nr[t] = s; __syncthreads();
        for (int off = 128; off; off >>= 1) {
            if (t < off) nr[t] += nr[t + off];
            __syncthreads();
        }
        if (t == 0) ws[OFF_NORMS + m] = nr[0];
        const float* ep = ws + OFF_EPART + (size_t)m * 4096;
        for (int i = t; i < 4096; i += 256) {
            float e = 0.f;
            #pragma unroll
            for (int c = 0; c < 8; ++c) e += ep[(size_t)c * 65536 + i];
            E[i] = e;
        }
        __syncthreads();
        for (int i = t; i < 64 * 17; i += 256) {
            int y = i / 17, j = i % 17;
            int x0 = max(0, j - 8), x1 = min(64, j + 56);
            float e = 0.f;
            for (int x = x0; x < x1; ++x) e += E[y * 64 + x];
            R[i] = e;
        }
        __syncthreads();
        float* scale = ws + OFF_SCALE + (size_t)m * NSHIFT;
        for (int idx = t; idx < NSHIFT; idx += 256) {
            int ii = idx / 17, j = idx % 17;
            int y0 = max(0, ii - 8), y1 = min(64, ii + 56);
            float e = 0.f;
            for (int y = y0; y < y1; ++y) e += R[y * 17 + j];
            scale[idx] = 1.f / fmaxf(sqrtf(e), 1e-12f);
        }
        return;
    }

    // ---- corr block (R0 structure: strip-major order, depth-1 A pipe) ----
    int bc  = b - 16;                  // 0..1087
    int csl = bc & 7;                  // XCD low bits: csl-locality per XCD
    int r2  = bc >> 3;
    int dyi = r2 % 17;                 // fast axis: L2 keeps strip working-set
    int hq  = r2 / 17;                 // 0..7
    int h0  = hq * 8;
    int wv = t >> 6, l = t & 63;
    int m16 = l & 15, q = l >> 4, jl = q >> 1, c8 = q & 1;
    int wbase = wv * 16;

    const unsigned short* sats = satp + (size_t)csl * SATP_SLICE_U16;
    const unsigned short* grds = grdb + (size_t)csl * GRD_SLICE_U16;
    const unsigned short* goff = grds + ((wbase + jl) * 16 + m16) * 16 + c8 * 8;
    int hl = max(0, 8 - dyi - h0), hu = min(8, 72 - dyi - h0);

    floatx4 acc[17];
    #pragma unroll
    for (int d = 0; d < 17; ++d) acc[d] = (floatx4)0.f;

    #define STAGE(hs, p)                                                            \
        do {                                                                        \
            _Pragma("unroll")                                                       \
            for (int i_ = 0; i_ < 10; ++i_) {                                       \
                const unsigned short* g_ = sats + (size_t)(hs) * 20480              \
                                         + wv * 5120 + i_ * 512 + l * 8;            \
                __builtin_amdgcn_global_load_lds((AS1 void*)(unsigned short*)g_,    \
                    (AS3 void*)(smem + (p) * 40960 + wv * 10240 + i_ * 1024 + l * 16), \
                    16, 0, 0);                                                      \
            }                                                                       \
        } while (0)

    if (hl < hu) {
        int hs0 = h0 + hl + dyi - 8;
        STAGE(hs0, 0);
        bf16x8 Bc[8], Bn[8];
        #pragma unroll
        for (int bi = 0; bi < 8; ++bi)
            Bc[bi] = *(const bf16x8*)(goff + (size_t)(h0 + hl) * 16384 + bi * 512);

        for (int hh = hl; hh < hu; ++hh) {
            __syncthreads();                     // staged buf[hh&1] ready
            int p = (hh - hl) & 1;
            if (hh + 1 < hu) {
                STAGE(hs0 + (hh - hl) + 1, p ^ 1);
                #pragma unroll
                for (int bi = 0; bi < 8; ++bi)
                    Bn[bi] = *(const bf16x8*)(goff + (size_t)(h0 + hh + 1) * 16384 + bi * 512);
            }
            const unsigned char* aptr = smem + p * 40960 + jl * 512 + m16 * 32 + c8 * 16;
            bf16x8 A = *(const bf16x8*)(aptr + (size_t)wbase * 512);
            #pragma unroll
            for (int wo = 0; wo < 31; ++wo) {    // slot = wbase + wo (+jl)
                bf16x8 An = A;
                if (wo < 30) An = *(const bf16x8*)(aptr + (size_t)(wbase + wo + 1) * 512);
                #pragma unroll
                for (int bi = 0; bi < 8; ++bi) {
                    const int dxi = wo - 2 * bi;   // compile-time after unroll
                    if (dxi >= 0 && dxi <= 16)
                        acc[dxi] = __builtin_amdgcn_mfma_f32_16x16x32_bf16(A, Bc[bi], acc[dxi], 0, 0, 0);
                }
                A = An;
            }
            #pragma unroll
            for (int bi = 0; bi < 8; ++bi) Bc[bi] = Bn[bi];
        }
    }
    #undef STAGE

    // ---- cross-wave reduction epilogue: part traffic /4 ----
    __syncthreads();                    // all waves done reading staged smem
    float* red = (float*)smem;          // 4*68*64*4 = 69632 B <= 81920
    #pragma unroll
    for (int dxi = 0; dxi < 17; ++dxi)
        #pragma unroll
        for (int r = 0; r < 4; ++r)
            red[(size_t)(wv * 68 + dxi * 4 + r) * 64 + l] = acc[dxi][r];
    __syncthreads();
    float* pw = part + (size_t)bc * 4352;
    #pragma unroll
    for (int k = 0; k < 17; ++k) {
        int row = wv * 17 + k;
        float s = red[(size_t)(0 * 68 + row) * 64 + l]
                + red[(size_t)(1 * 68 + row) * 64 + l]
                + red[(size_t)(2 * 68 + row) * 64 + l]
                + red[(size_t)(3 * 68 + row) * 64 + l];
        pw[(size_t)row * 64 + l] = s;
    }
}

// ---------------- K4: reduce + scale + sim-max + fused final --------------
__global__ void k_reduce(const float* __restrict__ part, float* __restrict__ ws,
                         float* __restrict__ out) {
    int b = blockIdx.x;            // 289
    int dyi = b / 17, dxi = b % 17;
    int t = threadIdx.x;
    int l = t & 63, r = t >> 6;
    size_t eo = (size_t)(dxi * 4 + r) * 64 + l;
    float s = 0.f;
    for (int hq = 0; hq < 8; ++hq) {
        #pragma unroll
        for (int csl = 0; csl < 8; ++csl) {
            size_t blk = (size_t)((hq * 17 + dyi) * 8 + csl);
            s += part[blk * 4352 + eo];
        }
    }
    int n = l & 15, q = l >> 4, m = q * 4 + r;
    float val = s * ws[OFF_SCALE + m * NSHIFT + dyi * 17 + dxi];
    int iv = __float_as_int(val);
    unsigned key = (iv >= 0) ? ((unsigned)iv | 0x80000000u) : (unsigned)(~iv);
    atomicMax((unsigned*)ws + OFF_KEY + m * 16 + n, key);

    // ---- last-block-done fused epilogue (was k_final) ----
    __shared__ unsigned done;
    __syncthreads();
    if (t == 0) {
        __threadfence();               // publish this block's atomicMax results
        done = atomicAdd((unsigned*)ws + OFF_CNT, 1u);
    }
    __syncthreads();
    if (done != 288) return;           // only the last-finishing block proceeds
    __threadfence();                   // acquire side

    __shared__ float dist_s[256];
    __shared__ float pos_s[16];
    __shared__ float red2[256];
    __shared__ float minv[16];
    unsigned u = atomicOr((unsigned*)ws + OFF_KEY + t, 0u);
    int iv2 = (u & 0x80000000u) ? (int)(u & 0x7fffffffu) : ~(int)u;
    float best = __int_as_float(iv2);
    int mm = t >> 4, nn = t & 15;
    float Ng  = sqrtf(ws[OFF_NORMS + nn]);
    float sim = best / fmaxf(Ng, 1e-12f);
    float d   = 2.f - 2.f * sim;
    dist_s[t] = d;
    if (mm == nn) pos_s[mm] = d;
    __syncthreads();

    float x1 = (pos_s[nn] - d) * 10.f;
    float x2 = (pos_s[mm] - d) * 10.f;
    float sp1 = x1 > 20.f ? x1 : log1pf(expf(x1));
    float sp2 = x2 > 20.f ? x2 : log1pf(expf(x2));
    red2[t] = sp1 + sp2;
    __syncthreads();
    for (int off = 128; off; off >>= 1) {
        if (t < off) red2[t] += red2[t + off];
        __syncthreads();
    }
    if (t < 16) {
        float mv = 1e30f;
        for (int k = 0; k < 16; ++k) mv = fminf(mv, dist_s[t * 16 + k]);
        minv[t] = mv;
    }
    __syncthreads();
    if (t == 0) {
        float psum = 0.f, msum = 0.f;
        for (int qq = 0; qq < 16; ++qq) { psum += pos_s[qq]; msum += minv[qq]; }
        out[0] = red2[0] / 48.f;
        out[1] = psum / 16.f;
        out[2] = msum / 16.f;
    }
}

extern "C" void kernel_launch(void* const* d_in, const int* in_sizes, int n_in,
                              void* d_out, int out_size, void* d_ws, size_t ws_size,
                              hipStream_t stream) {
    const float* sat = (const float*)d_in[0];
    const float* grd = (const float*)d_in[1];
    float* out = (float*)d_out;
    float* ws  = (float*)d_ws;
    const unsigned short* satp = (const unsigned short*)((char*)d_ws + OFF_SATP_B);
    const unsigned short* grdb = (const unsigned short*)((char*)d_ws + OFF_GRDB_B);
    float* part = (float*)((char*)d_ws + OFF_PART_B);

    k_prep  <<<1024,      256, 0, stream>>>(sat, grd, ws);
    k_corr  <<<NBLK_CORR, 256, 0, stream>>>(satp, grdb, part, ws);
    k_reduce<<<NSHIFT,    256, 0, stream>>>(part, ws, out);
}